// Round 1
// baseline (2445.991 us; speedup 1.0000x reference)
//
#include <hip/hip_runtime.h>

typedef unsigned short u16;

#define NTOK   200000
#define NB1    3125      // NTOK/64
#define NBLK2  625
#define BT2    320       // NTOK/NBLK2

__device__ __forceinline__ float bf2f(u16 u) {
    union { unsigned int i; float f; } v; v.i = ((unsigned int)u) << 16; return v.f;
}
__device__ __forceinline__ u16 f2bf(float f) {
    union { float f; unsigned int i; } v; v.f = f;
    unsigned int x = v.i;
    return (u16)((x + 0x7fffu + ((x >> 16) & 1u)) >> 16);
}

// ---------------------------------------------------------------------------
// K1: x_mid = x@Wx^T + bx (f32 out), fx_mid = x@Wfx^T + bfx (bf16 out)
// 64 tokens/block, 512 threads, per-thread 4 tok x 8 cols.
// ---------------------------------------------------------------------------
__global__ __launch_bounds__(512) void k1_dual(
    const float* __restrict__ x, const float* __restrict__ Wx,
    const float* __restrict__ bx, const float* __restrict__ Wfx,
    const float* __restrict__ bfx, float* __restrict__ xmid,
    u16* __restrict__ fxmid)
{
    __shared__ float xs[64 * 257];
    __shared__ float wt[64 * 257];
    const int tid = threadIdx.x;
    const long n0 = (long)blockIdx.x * 64;

    for (int i = tid; i < 64 * 256; i += 512)
        xs[(i >> 8) * 257 + (i & 255)] = x[n0 * 256 + i];

    const int trow = tid >> 5;   // 0..15
    const int tcol = tid & 31;   // 0..31

    for (int m = 0; m < 2; ++m) {
        const float* __restrict__ W    = m ? Wfx : Wx;
        const float* __restrict__ bias = m ? bfx : bx;

        float acc[4][8];
        #pragma unroll
        for (int j = 0; j < 8; ++j) {
            float b = bias[tcol * 8 + j];
            #pragma unroll
            for (int i = 0; i < 4; ++i) acc[i][j] = b;
        }

        for (int kt = 0; kt < 4; ++kt) {
            __syncthreads();
            // stage W^T tile: element (kk, c) at kk*257 + (c&7)*32 + (c>>3)
            for (int i = tid; i < 64 * 256; i += 512) {
                int c = i >> 6, kk = i & 63;
                wt[kk * 257 + (c & 7) * 32 + (c >> 3)] = W[c * 256 + kt * 64 + kk];
            }
            __syncthreads();
            #pragma unroll 4
            for (int kk = 0; kk < 64; ++kk) {
                float xv[4], wv[8];
                #pragma unroll
                for (int i = 0; i < 4; ++i)
                    xv[i] = xs[(trow * 4 + i) * 257 + kt * 64 + kk];
                #pragma unroll
                for (int j = 0; j < 8; ++j)
                    wv[j] = wt[kk * 257 + j * 32 + tcol];
                #pragma unroll
                for (int i = 0; i < 4; ++i)
                    #pragma unroll
                    for (int j = 0; j < 8; ++j)
                        acc[i][j] += xv[i] * wv[j];
            }
        }
        if (m == 0) {
            #pragma unroll
            for (int i = 0; i < 4; ++i) {
                long row = n0 + trow * 4 + i;
                float* yp = xmid + row * 256 + tcol * 8;
                float4 v0, v1;
                v0.x = acc[i][0]; v0.y = acc[i][1]; v0.z = acc[i][2]; v0.w = acc[i][3];
                v1.x = acc[i][4]; v1.y = acc[i][5]; v1.z = acc[i][6]; v1.w = acc[i][7];
                *(float4*)(yp)     = v0;
                *(float4*)(yp + 4) = v1;
            }
        } else {
            #pragma unroll
            for (int i = 0; i < 4; ++i) {
                long row = n0 + trow * 4 + i;
                u16* op = fxmid + row * 256 + tcol * 8;
                ushort4 u0, u1;
                u0.x = f2bf(acc[i][0]); u0.y = f2bf(acc[i][1]);
                u0.z = f2bf(acc[i][2]); u0.w = f2bf(acc[i][3]);
                u1.x = f2bf(acc[i][4]); u1.y = f2bf(acc[i][5]);
                u1.z = f2bf(acc[i][6]); u1.w = f2bf(acc[i][7]);
                *(ushort4*)(op)     = u0;
                *(ushort4*)(op + 4) = u1;
            }
        }
    }
}

// ---------------------------------------------------------------------------
// K2: per-token slice softmax weights + per-block partial
//     slice_token[h][g][c] and slice_norm[h][g].
// 256 threads: h = tid>>5 (wave owns 2 heads), t5 = tid&31.
// Weight exchange via intra-wave __shfl (no barriers in the token loop).
// ---------------------------------------------------------------------------
__global__ __launch_bounds__(256) void k2_slice(
    const float* __restrict__ xmid, const u16* __restrict__ fxmid,
    const float* __restrict__ Wslice, const float* __restrict__ bslice,
    const float* __restrict__ temperature,
    float* __restrict__ pst, float* __restrict__ pnorm)
{
    __shared__ float ws[64 * 36];   // Wslice, padded rows (float4-aligned)
    const int tid = threadIdx.x;
    for (int i = tid; i < 2048; i += 256)
        ws[(i >> 5) * 36 + (i & 31)] = Wslice[i];

    const int h  = tid >> 5;
    const int t5 = tid & 31;
    const int gq = t5 >> 2;     // g block: gq*8 .. gq*8+7
    const int cq = t5 & 3;      // c block: cq*8 .. cq*8+7
    const int srcbase = (h & 1) * 32 + (gq & 3) * 8;

    float tc = temperature[h];
    tc = fminf(fmaxf(tc, 0.1f), 5.0f);
    const float invt = 1.0f / tc;
    const float b0 = bslice[t5];
    const float b1 = bslice[t5 + 32];

    float acc[8][8];
    #pragma unroll
    for (int i = 0; i < 8; ++i)
        #pragma unroll
        for (int j = 0; j < 8; ++j) acc[i][j] = 0.f;
    float nacc0 = 0.f, nacc1 = 0.f;

    const long nbase = (long)blockIdx.x * BT2;
    __syncthreads();

    for (int tt = 0; tt < BT2; ++tt) {
        const long n = nbase + tt;
        float xv[32];
        const float4* xp = (const float4*)(xmid + n * 256 + h * 32);
        #pragma unroll
        for (int k4 = 0; k4 < 8; ++k4) {
            float4 u = xp[k4];
            xv[k4*4+0] = u.x; xv[k4*4+1] = u.y; xv[k4*4+2] = u.z; xv[k4*4+3] = u.w;
        }
        // two logits per thread: g = t5 and t5+32
        float l0 = b0, l1 = b1;
        #pragma unroll
        for (int k4 = 0; k4 < 8; ++k4) {
            float4 wa = *(const float4*)&ws[t5 * 36 + k4 * 4];
            float4 wb = *(const float4*)&ws[(t5 + 32) * 36 + k4 * 4];
            l0 += xv[k4*4+0]*wa.x + xv[k4*4+1]*wa.y + xv[k4*4+2]*wa.z + xv[k4*4+3]*wa.w;
            l1 += xv[k4*4+0]*wb.x + xv[k4*4+1]*wb.y + xv[k4*4+2]*wb.z + xv[k4*4+3]*wb.w;
        }
        l0 *= invt; l1 *= invt;
        // softmax over 64 g (32 lanes x 2). No max-subtraction: |logit| <~ 20.
        float e0 = __expf(l0), e1 = __expf(l1);
        float ssum = e0 + e1;
        #pragma unroll
        for (int d = 16; d > 0; d >>= 1) ssum += __shfl_xor(ssum, d);
        const float inv = 1.0f / ssum;
        const float w0v = e0 * inv, w1v = e1 * inv;
        nacc0 += w0v; nacc1 += w1v;

        // gather the 8 weights this thread accumulates with (intra-wave)
        float wv[8];
        #pragma unroll
        for (int i = 0; i < 8; ++i) {
            float a = __shfl(w0v, srcbase + i);
            float b = __shfl(w1v, srcbase + i);
            wv[i] = (gq < 4) ? a : b;
        }
        float fv[8];
        const ushort4* fp = (const ushort4*)(fxmid + n * 256 + h * 32 + cq * 8);
        ushort4 f0 = fp[0], f1 = fp[1];
        fv[0]=bf2f(f0.x); fv[1]=bf2f(f0.y); fv[2]=bf2f(f0.z); fv[3]=bf2f(f0.w);
        fv[4]=bf2f(f1.x); fv[5]=bf2f(f1.y); fv[6]=bf2f(f1.z); fv[7]=bf2f(f1.w);
        #pragma unroll
        for (int i = 0; i < 8; ++i)
            #pragma unroll
            for (int j = 0; j < 8; ++j)
                acc[i][j] += wv[i] * fv[j];
    }

    float* po = pst + (long)blockIdx.x * 16384 + (h * 64 + gq * 8) * 32 + cq * 8;
    #pragma unroll
    for (int i = 0; i < 8; ++i)
        #pragma unroll
        for (int j = 0; j < 8; ++j)
            po[i * 32 + j] = acc[i][j];
    pnorm[(long)blockIdx.x * 512 + h * 64 + t5]      = nacc0;
    pnorm[(long)blockIdx.x * 512 + h * 64 + t5 + 32] = nacc1;
}

// ---------------------------------------------------------------------------
// K2b: reduce partials, normalize slice_token by (norm + 1e-5)
// ---------------------------------------------------------------------------
__global__ __launch_bounds__(256) void k2b_reduce(
    const float* __restrict__ pst, const float* __restrict__ pnorm,
    float* __restrict__ stn)
{
    const int idx = blockIdx.x * 256 + threadIdx.x;   // 0..16383
    const int hg  = idx >> 5;
    float s = 0.f, nr = 0.f;
    for (int b = 0; b < NBLK2; ++b) {
        s  += pst[(long)b * 16384 + idx];
        nr += pnorm[(long)b * 512 + hg];
    }
    stn[idx] = s / (nr + 1e-5f);
}

// ---------------------------------------------------------------------------
// K3: tiny per-head attention over the 64 slice tokens. grid=8, block=64.
// ---------------------------------------------------------------------------
__global__ __launch_bounds__(64) void k3_attn(
    const float* __restrict__ stn, const float* __restrict__ Wq,
    const float* __restrict__ Wk, const float* __restrict__ Wv,
    float* __restrict__ os)
{
    __shared__ float kl[64 * 32];
    __shared__ float vl[64 * 32];
    const int h = blockIdx.x;
    const int g = threadIdx.x;
    float s[32];
    const float4* sp = (const float4*)(stn + (h * 64 + g) * 32);
    #pragma unroll
    for (int d4 = 0; d4 < 8; ++d4) {
        float4 v = sp[d4];
        s[d4*4+0]=v.x; s[d4*4+1]=v.y; s[d4*4+2]=v.z; s[d4*4+3]=v.w;
    }
    float q[32];
    #pragma unroll
    for (int e = 0; e < 32; ++e) {
        float aq = 0.f, ak = 0.f, av = 0.f;
        #pragma unroll
        for (int d = 0; d < 32; ++d) {
            aq += s[d] * Wq[e * 32 + d];
            ak += s[d] * Wk[e * 32 + d];
            av += s[d] * Wv[e * 32 + d];
        }
        q[e] = aq; kl[g * 32 + e] = ak; vl[g * 32 + e] = av;
    }
    __syncthreads();
    float p[64];
    float mx = -1e30f;
    const float scale = 0.17677669529663689f;  // 32^-0.5
    #pragma unroll
    for (int kk = 0; kk < 64; ++kk) {
        float a = 0.f;
        #pragma unroll
        for (int e = 0; e < 32; ++e) a += q[e] * kl[kk * 32 + e];
        a *= scale;
        p[kk] = a;
        mx = fmaxf(mx, a);
    }
    float sum = 0.f;
    #pragma unroll
    for (int kk = 0; kk < 64; ++kk) { p[kk] = __expf(p[kk] - mx); sum += p[kk]; }
    const float inv = 1.0f / sum;
    #pragma unroll
    for (int kk = 0; kk < 64; ++kk) p[kk] *= inv;
    #pragma unroll
    for (int d = 0; d < 32; ++d) {
        float a = 0.f;
        #pragma unroll
        for (int kk = 0; kk < 64; ++kk) a += p[kk] * vl[kk * 32 + d];
        os[(h * 64 + g) * 32 + d] = a;
    }
}

// ---------------------------------------------------------------------------
// K4a: recompute slice weights, out_x[n, h*32+c] = sum_g w[g]*os[h][g][c].
// Online (unnormalized-exp) accumulation: no w[64] register array.
// grid=3125, block=256 (h = tid>>5, two tokens per thread).
// ---------------------------------------------------------------------------
__global__ __launch_bounds__(256) void k4a_outx(
    const float* __restrict__ xmid, const float* __restrict__ os,
    const float* __restrict__ Wslice, const float* __restrict__ bslice,
    const float* __restrict__ temperature, u16* __restrict__ outx)
{
    __shared__ float osl[16384];
    const int tid = threadIdx.x;
    for (int i = tid; i < 16384; i += 256) osl[i] = os[i];
    const int h  = tid >> 5;
    const int t0 = tid & 31;
    float tc = fminf(fmaxf(temperature[h], 0.1f), 5.0f);
    const float invt = 1.0f / tc;
    const long n0 = (long)blockIdx.x * 64;
    __syncthreads();

    for (int u = 0; u < 2; ++u) {
        const long n = n0 + t0 + u * 32;
        float xv[32];
        const float4* xp = (const float4*)(xmid + n * 256 + h * 32);
        #pragma unroll
        for (int k4 = 0; k4 < 8; ++k4) {
            float4 uu = xp[k4];
            xv[k4*4+0]=uu.x; xv[k4*4+1]=uu.y; xv[k4*4+2]=uu.z; xv[k4*4+3]=uu.w;
        }
        float o[32];
        #pragma unroll
        for (int c = 0; c < 32; ++c) o[c] = 0.f;
        float sum = 0.f;
        #pragma unroll 2
        for (int g = 0; g < 64; ++g) {
            float l = bslice[g];
            #pragma unroll
            for (int k = 0; k < 32; ++k) l += xv[k] * Wslice[g * 32 + k];
            const float e = __expf(l * invt);
            sum += e;
            const float4* op4 = (const float4*)(osl + (h * 64 + g) * 32);
            #pragma unroll
            for (int c4 = 0; c4 < 8; ++c4) {
                float4 v = op4[c4];
                o[c4*4+0] += e * v.x; o[c4*4+1] += e * v.y;
                o[c4*4+2] += e * v.z; o[c4*4+3] += e * v.w;
            }
        }
        const float inv = 1.0f / sum;
        u16* yp = outx + n * 256 + h * 32;
        #pragma unroll
        for (int c4 = 0; c4 < 8; ++c4) {
            ushort4 uu;
            uu.x = f2bf(o[c4*4+0] * inv); uu.y = f2bf(o[c4*4+1] * inv);
            uu.z = f2bf(o[c4*4+2] * inv); uu.w = f2bf(o[c4*4+3] * inv);
            *(ushort4*)(yp + c4 * 4) = uu;
        }
    }
}

// ---------------------------------------------------------------------------
// K4b: out = out_x @ Wout^T + bout  (bf16 in, f32 out). Same tiling as K1.
// ---------------------------------------------------------------------------
__global__ __launch_bounds__(512) void k4b_gemm(
    const u16* __restrict__ outx, const float* __restrict__ Wout,
    const float* __restrict__ bout, float* __restrict__ y)
{
    __shared__ float xs[64 * 257];
    __shared__ float wt[64 * 257];
    const int tid = threadIdx.x;
    const long n0 = (long)blockIdx.x * 64;

    for (int i = tid; i < 8192; i += 512) {
        ushort2 u = ((const ushort2*)(outx + n0 * 256))[i];
        int t = i >> 7;
        int k = (i & 127) * 2;
        xs[t * 257 + k]     = bf2f(u.x);
        xs[t * 257 + k + 1] = bf2f(u.y);
    }
    const int trow = tid >> 5;
    const int tcol = tid & 31;

    float acc[4][8];
    #pragma unroll
    for (int j = 0; j < 8; ++j) {
        float b = bout[tcol * 8 + j];
        #pragma unroll
        for (int i = 0; i < 4; ++i) acc[i][j] = b;
    }

    for (int kt = 0; kt < 4; ++kt) {
        __syncthreads();
        for (int i = tid; i < 64 * 256; i += 512) {
            int c = i >> 6, kk = i & 63;
            wt[kk * 257 + (c & 7) * 32 + (c >> 3)] = Wout[c * 256 + kt * 64 + kk];
        }
        __syncthreads();
        #pragma unroll 4
        for (int kk = 0; kk < 64; ++kk) {
            float xv[4], wv[8];
            #pragma unroll
            for (int i = 0; i < 4; ++i)
                xv[i] = xs[(trow * 4 + i) * 257 + kt * 64 + kk];
            #pragma unroll
            for (int j = 0; j < 8; ++j)
                wv[j] = wt[kk * 257 + j * 32 + tcol];
            #pragma unroll
            for (int i = 0; i < 4; ++i)
                #pragma unroll
                for (int j = 0; j < 8; ++j)
                    acc[i][j] += xv[i] * wv[j];
        }
    }
    #pragma unroll
    for (int i = 0; i < 4; ++i) {
        long row = n0 + trow * 4 + i;
        float* yp = y + row * 256 + tcol * 8;
        float4 v0, v1;
        v0.x = acc[i][0]; v0.y = acc[i][1]; v0.z = acc[i][2]; v0.w = acc[i][3];
        v1.x = acc[i][4]; v1.y = acc[i][5]; v1.z = acc[i][6]; v1.w = acc[i][7];
        *(float4*)(yp)     = v0;
        *(float4*)(yp + 4) = v1;
    }
}

// ---------------------------------------------------------------------------
extern "C" void kernel_launch(void* const* d_in, const int* in_sizes, int n_in,
                              void* d_out, int out_size, void* d_ws, size_t ws_size,
                              hipStream_t stream) {
    const float* x       = (const float*)d_in[0];
    const float* Wx      = (const float*)d_in[1];
    const float* bx      = (const float*)d_in[2];
    const float* Wfx     = (const float*)d_in[3];
    const float* bfx     = (const float*)d_in[4];
    const float* Wslice  = (const float*)d_in[5];
    const float* bslice  = (const float*)d_in[6];
    const float* Wq      = (const float*)d_in[7];
    const float* Wk      = (const float*)d_in[8];
    const float* Wv      = (const float*)d_in[9];
    const float* Wout    = (const float*)d_in[10];
    const float* bout    = (const float*)d_in[11];
    const float* temp    = (const float*)d_in[12];

    char* w = (char*)d_ws;
    float* xmid  = (float*)(w);                        // 51.2M f32  (204,800,000 B)
    u16*   fxmid = (u16*)(w + 204800000);              // 51.2M bf16 (102,400,000 B)
    float* pst   = (float*)(w + 307200000);            // 625*16384 f32 (40,960,000 B)
    float* pnorm = (float*)(w + 348160000);            // 625*512 f32 (1,280,000 B)
    float* stn   = (float*)(w + 349440000);            // 16384 f32
    float* os    = (float*)(w + 349505536);            // 16384 f32
    u16*   outxb = fxmid;                              // reuse: fxmid dead after K2
    float* y     = (float*)d_out;

    k1_dual<<<NB1, 512, 0, stream>>>(x, Wx, bx, Wfx, bfx, xmid, fxmid);
    k2_slice<<<NBLK2, 256, 0, stream>>>(xmid, fxmid, Wslice, bslice, temp, pst, pnorm);
    k2b_reduce<<<64, 256, 0, stream>>>(pst, pnorm, stn);
    k3_attn<<<8, 64, 0, stream>>>(stn, Wq, Wk, Wv, os);
    k4a_outx<<<NB1, 256, 0, stream>>>(xmid, os, Wslice, bslice, temp, outxb);
    k4b_gemm<<<NB1, 512, 0, stream>>>(outxb, Wout, bout, y);
}

// Round 2
// 1392.933 us; speedup vs baseline: 1.7560x; 1.7560x over previous
//
#include <hip/hip_runtime.h>

typedef unsigned short u16;
typedef __attribute__((ext_vector_type(4))) float f32x4;
typedef __attribute__((ext_vector_type(8))) short bf16x8;  // 8 bf16 bits in 4 VGPRs

__device__ __forceinline__ float bf2f(u16 u) {
    union { unsigned int i; float f; } v; v.i = ((unsigned int)u) << 16; return v.f;
}
__device__ __forceinline__ u16 f2bf(float f) {
    union { float f; unsigned int i; } v; v.f = f;
    unsigned int x = v.i;
    return (u16)((x + 0x7fffu + ((x >> 16) & 1u)) >> 16);
}

__device__ __forceinline__ f32x4 MFMA(bf16x8 a, bf16x8 b, f32x4 c) {
    return __builtin_amdgcn_mfma_f32_16x16x32_bf16(a, b, c, 0, 0, 0);
}

// ---------------------------------------------------------------------------
// kprep: Wcomb[hg][k] = invt_h * sum_d Wslice[g,d]*Wx[h*32+d,k]  (bf16)
//        bcomb[hg]    = invt_h * (sum_d Wslice[g,d]*bx[h*32+d] + bslice[g])
//        WfxT = bf16(Wfx)   (already [col][k] = B^T layout)
// ---------------------------------------------------------------------------
__global__ __launch_bounds__(256) void kprep(
    const float* __restrict__ Wx, const float* __restrict__ bx,
    const float* __restrict__ Wfx, const float* __restrict__ Wslice,
    const float* __restrict__ bslice, const float* __restrict__ temperature,
    u16* __restrict__ Wcomb, float* __restrict__ bcomb, u16* __restrict__ WfxT)
{
    const int gidx = blockIdx.x * 256 + threadIdx.x;
    if (gidx < 131072) {
        const int hg = gidx >> 8, k = gidx & 255;
        const int h = hg >> 6, g = hg & 63;
        float tc = fminf(fmaxf(temperature[h], 0.1f), 5.0f);
        const float invt = 1.0f / tc;
        float s = 0.f;
        #pragma unroll
        for (int d = 0; d < 32; ++d) s += Wslice[g * 32 + d] * Wx[(h * 32 + d) * 256 + k];
        Wcomb[hg * 256 + k] = f2bf(s * invt);
    } else if (gidx < 131072 + 65536) {
        const int i = gidx - 131072;
        WfxT[i] = f2bf(Wfx[i]);
    } else if (gidx < 131072 + 65536 + 512) {
        const int hg = gidx - 131072 - 65536;
        const int h = hg >> 6, g = hg & 63;
        float tc = fminf(fmaxf(temperature[h], 0.1f), 5.0f);
        float s = bslice[g];
        #pragma unroll
        for (int d = 0; d < 32; ++d) s += Wslice[g * 32 + d] * bx[h * 32 + d];
        bcomb[hg] = s / tc;
    }
}

// ---------------------------------------------------------------------------
// kAB: fused fx-GEMM + logits-GEMM + softmax + sw store + slice_token partials.
// 512 threads (8 waves; wave w = head w). Grid 512, 6-7 x 64-token tiles each.
// LDS: [0,64K) A_hi/A_lo (reused as wT per head), [64K,96K) fxT per head.
// ---------------------------------------------------------------------------
__global__ __launch_bounds__(512, 2) void kAB(
    const float* __restrict__ x, const u16* __restrict__ Wcomb,
    const float* __restrict__ bcomb, const u16* __restrict__ WfxT,
    const float* __restrict__ bfx,
    u16* __restrict__ swg, float* __restrict__ pst, float* __restrict__ pnorm)
{
    __shared__ char lds[98304];
    const int tid = threadIdx.x;
    const int w   = tid >> 6;       // wave = head
    const int lane = tid & 63;
    const int l15 = lane & 15;
    const int l4  = lane >> 4;      // 0..3
    const int aswz = (l15 & 7) << 4;

    float bc[4];
    #pragma unroll
    for (int fc = 0; fc < 4; ++fc) bc[fc] = bcomb[w * 64 + fc * 16 + l15];
    float bfv[2];
    #pragma unroll
    for (int fc = 0; fc < 2; ++fc) bfv[fc] = bfx[w * 32 + fc * 16 + l15];

    f32x4 stacc[2][4];
    #pragma unroll
    for (int i = 0; i < 2; ++i)
        #pragma unroll
        for (int j = 0; j < 4; ++j) stacc[i][j] = (f32x4){0.f, 0.f, 0.f, 0.f};
    float nacc[4] = {0.f, 0.f, 0.f, 0.f};

    const int bid   = blockIdx.x;
    const int cnt   = 6 + (bid < 53 ? 1 : 0);
    const int tbase = bid * 6 + (bid < 53 ? bid : 53);

    const int srow  = tid >> 3;          // staging: row 0..63
    const int skseg = (tid & 7) * 32;    // staging: k element base
    const int sswz  = (srow & 7) << 4;
    const int sbase = srow * 512 + skseg * 2;

    for (int t = 0; t < cnt; ++t) {
        const long tok0 = (long)(tbase + t) * 64;

        // ---- P0: stage A hi/lo (f32 -> bf16 split, XOR-swizzled rows) ----
        {
            const float4* xp = (const float4*)(x + (tok0 + srow) * 256 + skseg);
            #pragma unroll
            for (int c = 0; c < 4; ++c) {
                float4 a = xp[2 * c], b = xp[2 * c + 1];
                float vv[8] = {a.x, a.y, a.z, a.w, b.x, b.y, b.z, b.w};
                unsigned int hw[4], lw[4];
                #pragma unroll
                for (int j = 0; j < 4; ++j) {
                    u16 h0 = f2bf(vv[2 * j]);     u16 q0 = f2bf(vv[2 * j]     - bf2f(h0));
                    u16 h1 = f2bf(vv[2 * j + 1]); u16 q1 = f2bf(vv[2 * j + 1] - bf2f(h1));
                    hw[j] = (unsigned int)h0 | ((unsigned int)h1 << 16);
                    lw[j] = (unsigned int)q0 | ((unsigned int)q1 << 16);
                }
                const int addr = (sbase + c * 16) ^ sswz;
                *(uint4*)(lds + addr)         = make_uint4(hw[0], hw[1], hw[2], hw[3]);
                *(uint4*)(lds + 32768 + addr) = make_uint4(lw[0], lw[1], lw[2], lw[3]);
            }
        }
        __syncthreads();

        // ---- P1: fx = x @ Wfx^T + bfx  (hi product only; output is bf16 anyway)
        f32x4 accF[4][2];
        #pragma unroll
        for (int mt = 0; mt < 4; ++mt)
            #pragma unroll
            for (int fc = 0; fc < 2; ++fc)
                accF[mt][fc] = (f32x4){bfv[fc], bfv[fc], bfv[fc], bfv[fc]};
        #pragma unroll
        for (int ks = 0; ks < 8; ++ks) {
            bf16x8 bfrag[2];
            #pragma unroll
            for (int fc = 0; fc < 2; ++fc)
                bfrag[fc] = *(const bf16x8*)(WfxT + (size_t)(w * 32 + fc * 16 + l15) * 256 + ks * 32 + l4 * 8);
            bf16x8 ah[4];
            #pragma unroll
            for (int mt = 0; mt < 4; ++mt)
                ah[mt] = *(const bf16x8*)(lds + (mt * 16 + l15) * 512 + ((ks * 64 + l4 * 16) ^ aswz));
            #pragma unroll
            for (int mt = 0; mt < 4; ++mt)
                #pragma unroll
                for (int fc = 0; fc < 2; ++fc)
                    accF[mt][fc] = MFMA(ah[mt], bfrag[fc], accF[mt][fc]);
        }

        // ---- P2: logits = x @ Wcomb^T + bcomb (hi+lo split on A) ----
        f32x4 accL[4][4];
        #pragma unroll
        for (int mt = 0; mt < 4; ++mt)
            #pragma unroll
            for (int fc = 0; fc < 4; ++fc)
                accL[mt][fc] = (f32x4){bc[fc], bc[fc], bc[fc], bc[fc]};
        #pragma unroll
        for (int ks = 0; ks < 8; ++ks) {
            bf16x8 bw[4];
            #pragma unroll
            for (int fc = 0; fc < 4; ++fc)
                bw[fc] = *(const bf16x8*)(Wcomb + (size_t)(w * 64 + fc * 16 + l15) * 256 + ks * 32 + l4 * 8);
            bf16x8 ah[4], al[4];
            #pragma unroll
            for (int mt = 0; mt < 4; ++mt) {
                const int off = (mt * 16 + l15) * 512 + ((ks * 64 + l4 * 16) ^ aswz);
                ah[mt] = *(const bf16x8*)(lds + off);
                al[mt] = *(const bf16x8*)(lds + 32768 + off);
            }
            #pragma unroll
            for (int mt = 0; mt < 4; ++mt)
                #pragma unroll
                for (int fc = 0; fc < 4; ++fc) {
                    accL[mt][fc] = MFMA(ah[mt], bw[fc], accL[mt][fc]);
                    accL[mt][fc] = MFMA(al[mt], bw[fc], accL[mt][fc]);
                }
        }
        __syncthreads();   // all waves done reading A region

        // ---- P3: per-row softmax over 64 g (4 frag regs x 16 lanes) ----
        float pn[4] = {0.f, 0.f, 0.f, 0.f};
        #pragma unroll
        for (int mt = 0; mt < 4; ++mt) {
            #pragma unroll
            for (int r = 0; r < 4; ++r) {
                float v0 = accL[mt][0][r], v1 = accL[mt][1][r];
                float v2 = accL[mt][2][r], v3 = accL[mt][3][r];
                float m = fmaxf(fmaxf(v0, v1), fmaxf(v2, v3));
                m = fmaxf(m, __shfl_xor(m, 1));
                m = fmaxf(m, __shfl_xor(m, 2));
                m = fmaxf(m, __shfl_xor(m, 4));
                m = fmaxf(m, __shfl_xor(m, 8));
                float e0 = __expf(v0 - m), e1 = __expf(v1 - m);
                float e2 = __expf(v2 - m), e3 = __expf(v3 - m);
                float s = e0 + e1 + e2 + e3;
                s += __shfl_xor(s, 1); s += __shfl_xor(s, 2);
                s += __shfl_xor(s, 4); s += __shfl_xor(s, 8);
                const float inv = 1.0f / s;
                e0 *= inv; e1 *= inv; e2 *= inv; e3 *= inv;
                accL[mt][0][r] = e0; accL[mt][1][r] = e1;
                accL[mt][2][r] = e2; accL[mt][3][r] = e3;
                pn[0] += e0; pn[1] += e1; pn[2] += e2; pn[3] += e3;
            }
        }
        #pragma unroll
        for (int fc = 0; fc < 4; ++fc) {
            float v = pn[fc];
            v += __shfl_xor(v, 16); v += __shfl_xor(v, 32);
            nacc[fc] += v;
        }

        // ---- P4: sw -> global; wT, fxT -> swizzled LDS (over A region) ----
        #pragma unroll
        for (int mt = 0; mt < 4; ++mt) {
            #pragma unroll
            for (int r = 0; r < 4; ++r) {
                const int nloc = mt * 16 + l4 * 4 + r;
                #pragma unroll
                for (int fc = 0; fc < 4; ++fc) {
                    const u16 wb = f2bf(accL[mt][fc][r]);
                    const int g = fc * 16 + l15;
                    swg[(tok0 + nloc) * 512 + w * 64 + g] = wb;
                    *(u16*)(lds + ((w * 8192 + g * 128 + nloc * 2) ^ ((g & 7) << 4))) = wb;
                }
                #pragma unroll
                for (int fc = 0; fc < 2; ++fc) {
                    const u16 fb = f2bf(accF[mt][fc][r]);
                    const int c = fc * 16 + l15;
                    *(u16*)(lds + 65536 + ((w * 4096 + c * 128 + nloc * 2) ^ ((c & 7) << 4))) = fb;
                }
            }
        }
        __syncthreads();

        // ---- P5: slice_token partial: st[c][g] += fxT * wT over 64 tokens ----
        #pragma unroll
        for (int ks2 = 0; ks2 < 2; ++ks2) {
            bf16x8 fa[2], wb2[4];
            #pragma unroll
            for (int mt2 = 0; mt2 < 2; ++mt2) {
                const int c = mt2 * 16 + l15;
                fa[mt2] = *(const bf16x8*)(lds + 65536 +
                    ((w * 4096 + c * 128 + ks2 * 64 + l4 * 16) ^ ((c & 7) << 4)));
            }
            #pragma unroll
            for (int nt = 0; nt < 4; ++nt) {
                const int g = nt * 16 + l15;
                wb2[nt] = *(const bf16x8*)(lds +
                    ((w * 8192 + g * 128 + ks2 * 64 + l4 * 16) ^ ((g & 7) << 4)));
            }
            #pragma unroll
            for (int mt2 = 0; mt2 < 2; ++mt2)
                #pragma unroll
                for (int nt = 0; nt < 4; ++nt)
                    stacc[mt2][nt] = MFMA(fa[mt2], wb2[nt], stacc[mt2][nt]);
        }
        __syncthreads();   // wT/fxT dead before next P0 overwrites
    }

    // ---- epilogue: partial slice_token + norm ----
    float* pstp = pst + ((size_t)bid * 8 + w) * 2048;
    #pragma unroll
    for (int mt2 = 0; mt2 < 2; ++mt2)
        #pragma unroll
        for (int nt = 0; nt < 4; ++nt)
            #pragma unroll
            for (int r = 0; r < 4; ++r) {
                const int c = mt2 * 16 + l4 * 4 + r;
                const int g = nt * 16 + l15;
                pstp[c * 64 + g] = stacc[mt2][nt][r];
            }
    if (l4 == 0) {
        #pragma unroll
        for (int fc = 0; fc < 4; ++fc)
            pnorm[(size_t)bid * 512 + w * 64 + fc * 16 + l15] = nacc[fc];
    }
}

// ---------------------------------------------------------------------------
// kC1: reduce pst partials (512) -> stn (raw slice_token numerator, [h][c][g])
// ---------------------------------------------------------------------------
__global__ __launch_bounds__(256) void kC1(
    const float* __restrict__ pst, float* __restrict__ stn)
{
    __shared__ float red[256];
    const int o = blockIdx.x * 128 + (threadIdx.x & 127);
    const int half = threadIdx.x >> 7;
    float s = 0.f;
    for (int b = half * 256; b < half * 256 + 256; ++b)
        s += pst[(size_t)b * 16384 + o];
    red[threadIdx.x] = s;
    __syncthreads();
    if (half == 0) stn[o] = red[threadIdx.x] + red[threadIdx.x + 128];
}

// ---------------------------------------------------------------------------
// kattn: norm reduce + tiny per-head attention over 64 slice tokens
// ---------------------------------------------------------------------------
__global__ __launch_bounds__(64) void kattn(
    const float* __restrict__ stn, const float* __restrict__ pnorm,
    const float* __restrict__ Wq, const float* __restrict__ Wk,
    const float* __restrict__ Wv, float* __restrict__ os)
{
    __shared__ float kl[2048], vl[2048];
    const int h = blockIdx.x, g = threadIdx.x;
    float ng = 0.f;
    for (int b = 0; b < 512; ++b) ng += pnorm[b * 512 + h * 64 + g];
    ng += 1e-5f;
    float s[32];
    #pragma unroll
    for (int d = 0; d < 32; ++d) s[d] = stn[h * 2048 + d * 64 + g] / ng;
    float q[32];
    #pragma unroll
    for (int e = 0; e < 32; ++e) {
        float aq = 0.f, ak = 0.f, av = 0.f;
        #pragma unroll
        for (int d = 0; d < 32; ++d) {
            aq += s[d] * Wq[e * 32 + d];
            ak += s[d] * Wk[e * 32 + d];
            av += s[d] * Wv[e * 32 + d];
        }
        q[e] = aq; kl[g * 32 + e] = ak; vl[g * 32 + e] = av;
    }
    __syncthreads();
    float p[64];
    float mx = -1e30f;
    const float scale = 0.17677669529663689f;
    #pragma unroll
    for (int kk = 0; kk < 64; ++kk) {
        float a = 0.f;
        #pragma unroll
        for (int e = 0; e < 32; ++e) a += q[e] * kl[kk * 32 + e];
        a *= scale; p[kk] = a; mx = fmaxf(mx, a);
    }
    float sum = 0.f;
    #pragma unroll
    for (int kk = 0; kk < 64; ++kk) { p[kk] = __expf(p[kk] - mx); sum += p[kk]; }
    const float inv = 1.0f / sum;
    #pragma unroll
    for (int d = 0; d < 32; ++d) {
        float a = 0.f;
        #pragma unroll
        for (int kk = 0; kk < 64; ++kk) a += p[kk] * inv * vl[kk * 32 + d];
        os[h * 2048 + g * 32 + d] = a;
    }
}

// ---------------------------------------------------------------------------
// kD2: Wc2T[co][hg] = sum_d os[h,g,d] * Wout[co, h*32+d]   (bf16)
// ---------------------------------------------------------------------------
__global__ __launch_bounds__(64) void kD2(
    const float* __restrict__ os, const float* __restrict__ Wout,
    u16* __restrict__ Wc2T)
{
    const int co = blockIdx.x;
    for (int rep = 0; rep < 8; ++rep) {
        const int hg = rep * 64 + threadIdx.x;
        const int h = hg >> 6, g = hg & 63;
        float s = 0.f;
        #pragma unroll
        for (int d = 0; d < 32; ++d)
            s += os[h * 2048 + g * 32 + d] * Wout[co * 256 + h * 32 + d];
        Wc2T[co * 512 + hg] = f2bf(s);
    }
}

// ---------------------------------------------------------------------------
// kE: out = sw @ Wc2T^T + bout  ([200000,512]x[512,256] bf16 MFMA, f32 out)
// ---------------------------------------------------------------------------
__global__ __launch_bounds__(512) void kE(
    const u16* __restrict__ swg, const u16* __restrict__ Wc2T,
    const float* __restrict__ bout, float* __restrict__ y)
{
    __shared__ char lds[65536];
    const int tid = threadIdx.x;
    const int w = tid >> 6;
    const int lane = tid & 63;
    const int l15 = lane & 15;
    const int l4 = lane >> 4;
    const long tok0 = (long)blockIdx.x * 64;

    {
        const int row = tid >> 3, seg = tid & 7;
        const uint4* sp = (const uint4*)(swg + (tok0 + row) * 512 + seg * 64);
        const int base = row * 1024 + seg * 128;
        const int swz = (row & 7) << 4;
        #pragma unroll
        for (int c = 0; c < 8; ++c) {
            uint4 v = sp[c];
            *(uint4*)(lds + ((base + c * 16) ^ swz)) = v;
        }
    }
    __syncthreads();

    const float b0 = bout[w * 32 + l15], b1 = bout[w * 32 + 16 + l15];
    f32x4 acc[4][2];
    #pragma unroll
    for (int mt = 0; mt < 4; ++mt) {
        acc[mt][0] = (f32x4){b0, b0, b0, b0};
        acc[mt][1] = (f32x4){b1, b1, b1, b1};
    }

    const int aswz = (l15 & 7) << 4;
    #pragma unroll 4
    for (int ks = 0; ks < 16; ++ks) {
        bf16x8 bfrag[2];
        #pragma unroll
        for (int fc = 0; fc < 2; ++fc)
            bfrag[fc] = *(const bf16x8*)(Wc2T + (size_t)(w * 32 + fc * 16 + l15) * 512 + ks * 32 + l4 * 8);
        bf16x8 a[4];
        #pragma unroll
        for (int mt = 0; mt < 4; ++mt)
            a[mt] = *(const bf16x8*)(lds + (mt * 16 + l15) * 1024 + ((ks * 64 + l4 * 16) ^ aswz));
        #pragma unroll
        for (int mt = 0; mt < 4; ++mt)
            #pragma unroll
            for (int fc = 0; fc < 2; ++fc)
                acc[mt][fc] = MFMA(a[mt], bfrag[fc], acc[mt][fc]);
    }

    #pragma unroll
    for (int mt = 0; mt < 4; ++mt)
        #pragma unroll
        for (int fc = 0; fc < 2; ++fc)
            #pragma unroll
            for (int r = 0; r < 4; ++r) {
                const long n = tok0 + mt * 16 + l4 * 4 + r;
                y[n * 256 + w * 32 + fc * 16 + l15] = acc[mt][fc][r];
            }
}

// ---------------------------------------------------------------------------
extern "C" void kernel_launch(void* const* d_in, const int* in_sizes, int n_in,
                              void* d_out, int out_size, void* d_ws, size_t ws_size,
                              hipStream_t stream) {
    const float* x       = (const float*)d_in[0];
    const float* Wx      = (const float*)d_in[1];
    const float* bx      = (const float*)d_in[2];
    const float* Wfx     = (const float*)d_in[3];
    const float* bfx     = (const float*)d_in[4];
    const float* Wslice  = (const float*)d_in[5];
    const float* bslice  = (const float*)d_in[6];
    const float* Wq      = (const float*)d_in[7];
    const float* Wk      = (const float*)d_in[8];
    const float* Wv      = (const float*)d_in[9];
    const float* Wout    = (const float*)d_in[10];
    const float* bout    = (const float*)d_in[11];
    const float* temp    = (const float*)d_in[12];

    char* wsb = (char*)d_ws;
    u16*   sw    = (u16*)(wsb);                      // 204,800,000 B
    float* pst   = (float*)(wsb + 204800000);        //  33,554,432 B
    float* pnorm = (float*)(wsb + 238354432);        //   1,048,576 B
    u16*   Wcomb = (u16*)(wsb + 239403008);          //     262,144 B
    float* bcomb = (float*)(wsb + 239665152);        //       2,048 B
    u16*   WfxT  = (u16*)(wsb + 239667200);          //     131,072 B
    u16*   Wc2T  = (u16*)(wsb + 239798272);          //     262,144 B
    float* os    = (float*)(wsb + 240060416);        //      65,536 B
    float* stn   = (float*)(wsb + 240125952);        //      65,536 B
    float* y     = (float*)d_out;

    kprep<<<770, 256, 0, stream>>>(Wx, bx, Wfx, Wslice, bslice, temp, Wcomb, bcomb, WfxT);
    kAB<<<512, 512, 0, stream>>>(x, Wcomb, bcomb, WfxT, bfx, sw, pst, pnorm);
    kC1<<<128, 256, 0, stream>>>(pst, stn);
    kattn<<<8, 64, 0, stream>>>(stn, pnorm, Wq, Wk, Wv, os);
    kD2<<<256, 64, 0, stream>>>(os, Wout, Wc2T);
    kE<<<3125, 512, 0, stream>>>(sw, Wc2T, bout, y);
}

// Round 3
// 1345.687 us; speedup vs baseline: 1.8177x; 1.0351x over previous
//
#include <hip/hip_runtime.h>

typedef unsigned short u16;
typedef __attribute__((ext_vector_type(4))) float f32x4;
typedef __attribute__((ext_vector_type(8))) short bf16x8;
typedef __attribute__((ext_vector_type(4))) unsigned int u32x4;

__device__ __forceinline__ float bf2f(u16 u) {
    union { unsigned int i; float f; } v; v.i = ((unsigned int)u) << 16; return v.f;
}
__device__ __forceinline__ u16 f2bf(float f) {
    union { float f; unsigned int i; } v; v.f = f;
    unsigned int x = v.i;
    return (u16)((x + 0x7fffu + ((x >> 16) & 1u)) >> 16);
}
__device__ __forceinline__ unsigned int pack2(float a, float b) {
    return (unsigned int)f2bf(a) | ((unsigned int)f2bf(b) << 16);
}
__device__ __forceinline__ void split2(float a, float b, unsigned int& h, unsigned int& l) {
    u16 ha = f2bf(a), hb = f2bf(b);
    u16 la = f2bf(a - bf2f(ha)), lb = f2bf(b - bf2f(hb));
    h = (unsigned int)ha | ((unsigned int)hb << 16);
    l = (unsigned int)la | ((unsigned int)lb << 16);
}

__device__ __forceinline__ f32x4 MFMA(bf16x8 a, bf16x8 b, f32x4 c) {
    return __builtin_amdgcn_mfma_f32_16x16x32_bf16(a, b, c, 0, 0, 0);
}

// ---------------------------------------------------------------------------
// kprep: Wcomb[hg][k] = invt_h * sum_d Wslice[g,d]*Wx[h*32+d,k]  (bf16)
//        bcomb[hg]    = invt_h * (sum_d Wslice[g,d]*bx[h*32+d] + bslice[g])
//        WfxT = bf16(Wfx)
// ---------------------------------------------------------------------------
__global__ __launch_bounds__(256) void kprep(
    const float* __restrict__ Wx, const float* __restrict__ bx,
    const float* __restrict__ Wfx, const float* __restrict__ Wslice,
    const float* __restrict__ bslice, const float* __restrict__ temperature,
    u16* __restrict__ Wcomb, float* __restrict__ bcomb, u16* __restrict__ WfxT)
{
    const int gidx = blockIdx.x * 256 + threadIdx.x;
    if (gidx < 131072) {
        const int hg = gidx >> 8, k = gidx & 255;
        const int h = hg >> 6, g = hg & 63;
        float tc = fminf(fmaxf(temperature[h], 0.1f), 5.0f);
        const float invt = 1.0f / tc;
        float s = 0.f;
        #pragma unroll
        for (int d = 0; d < 32; ++d) s += Wslice[g * 32 + d] * Wx[(h * 32 + d) * 256 + k];
        Wcomb[hg * 256 + k] = f2bf(s * invt);
    } else if (gidx < 131072 + 65536) {
        const int i = gidx - 131072;
        WfxT[i] = f2bf(Wfx[i]);
    } else if (gidx < 131072 + 65536 + 512) {
        const int hg = gidx - 131072 - 65536;
        const int h = hg >> 6, g = hg & 63;
        float tc = fminf(fmaxf(temperature[h], 0.1f), 5.0f);
        float s = bslice[g];
        #pragma unroll
        for (int d = 0; d < 32; ++d) s += Wslice[g * 32 + d] * bx[h * 32 + d];
        bcomb[hg] = s / tc;
    }
}

// ---------------------------------------------------------------------------
// kAB v3: 32-token tiles, 512 thr (wave=head), 64KB LDS, register-only P5.
// LDS: [0,16K) x-hi bf16 [32][256], [16K,32K) x-lo, [32K,64K) sw image.
// ---------------------------------------------------------------------------
__global__ __launch_bounds__(512, 4) void kAB(
    const float* __restrict__ x, const u16* __restrict__ Wcomb,
    const float* __restrict__ bcomb, const u16* __restrict__ WfxT,
    const float* __restrict__ bfx,
    u16* __restrict__ swg, float* __restrict__ pst, float* __restrict__ pnorm)
{
    __shared__ char lds[65536];
    const int tid  = threadIdx.x;
    const int w    = tid >> 6;
    const int lane = tid & 63;
    const int l15  = lane & 15;
    const int l4   = lane >> 4;
    const int aswz = (l15 & 7) << 4;

    float bc[4], bfv[2];
    #pragma unroll
    for (int fc = 0; fc < 4; ++fc) bc[fc] = bcomb[w * 64 + fc * 16 + l15];
    #pragma unroll
    for (int fc = 0; fc < 2; ++fc) bfv[fc] = bfx[w * 32 + fc * 16 + l15];

    f32x4 stacc[2][4];
    #pragma unroll
    for (int i = 0; i < 2; ++i)
        #pragma unroll
        for (int j = 0; j < 4; ++j) stacc[i][j] = (f32x4){0.f, 0.f, 0.f, 0.f};
    float nacc[4] = {0.f, 0.f, 0.f, 0.f};

    const int bid  = blockIdx.x;
    const int cnt  = 12 + (bid < 106 ? 1 : 0);     // 512*12 + 106 = 6250 tiles
    const long tb  = (long)bid * 12 + (bid < 106 ? bid : 106);

    const int srow = tid >> 4;                      // 0..31
    const int sseg = tid & 15;                      // 0..15
    const int skey = ((((srow >> 2) & 3) ^ (srow & 3)) << 4);
    const int sbs  = srow * 512 + sseg * 32;
    const int sswz = (srow & 7) << 4;

    float4 pf0, pf1, pf2, pf3;
    {
        const float4* xp = (const float4*)(x + (tb * 32 + srow) * 256 + sseg * 16);
        pf0 = xp[0]; pf1 = xp[1]; pf2 = xp[2]; pf3 = xp[3];
    }

    for (int t = 0; t < cnt; ++t) {
        const long tok0 = (tb + t) * 32;

        if (t) {
            __syncthreads();
            // copy out previous tile's sw image: full-line coalesced rows
            uint4* dst = (uint4*)(swg + (tok0 - 32 + srow) * 512);
            #pragma unroll
            for (int q = 0; q < 4; ++q)
                dst[q * 16 + sseg] =
                    *(const uint4*)(lds + 32768 + ((srow * 1024 + q * 256 + sseg * 16) ^ skey));
        }
        // stage A (hi/lo) from prefetch regs
        {
            unsigned int hw[8], lw[8];
            float4 vv0 = pf0, vv1 = pf1, vv2 = pf2, vv3 = pf3;
            split2(vv0.x, vv0.y, hw[0], lw[0]); split2(vv0.z, vv0.w, hw[1], lw[1]);
            split2(vv1.x, vv1.y, hw[2], lw[2]); split2(vv1.z, vv1.w, hw[3], lw[3]);
            split2(vv2.x, vv2.y, hw[4], lw[4]); split2(vv2.z, vv2.w, hw[5], lw[5]);
            split2(vv3.x, vv3.y, hw[6], lw[6]); split2(vv3.z, vv3.w, hw[7], lw[7]);
            *(uint4*)(lds + (sbs ^ sswz))                = make_uint4(hw[0], hw[1], hw[2], hw[3]);
            *(uint4*)(lds + ((sbs + 16) ^ sswz))         = make_uint4(hw[4], hw[5], hw[6], hw[7]);
            *(uint4*)(lds + 16384 + (sbs ^ sswz))        = make_uint4(lw[0], lw[1], lw[2], lw[3]);
            *(uint4*)(lds + 16384 + ((sbs + 16) ^ sswz)) = make_uint4(lw[4], lw[5], lw[6], lw[7]);
        }
        __syncthreads();

        // merged fx + logits GEMMs over K=256
        f32x4 accF[2][2], accL[2][4];
        #pragma unroll
        for (int mt = 0; mt < 2; ++mt) {
            #pragma unroll
            for (int fc = 0; fc < 2; ++fc)
                accF[mt][fc] = (f32x4){bfv[fc], bfv[fc], bfv[fc], bfv[fc]};
            #pragma unroll
            for (int fc = 0; fc < 4; ++fc)
                accL[mt][fc] = (f32x4){bc[fc], bc[fc], bc[fc], bc[fc]};
        }
        #pragma unroll
        for (int ks = 0; ks < 8; ++ks) {
            bf16x8 bfF[2], bw[4], ah[2], al[2];
            #pragma unroll
            for (int fc = 0; fc < 2; ++fc)
                bfF[fc] = *(const bf16x8*)(WfxT + (size_t)(w * 32 + fc * 16 + l15) * 256 + ks * 32 + l4 * 8);
            #pragma unroll
            for (int fc = 0; fc < 4; ++fc)
                bw[fc] = *(const bf16x8*)(Wcomb + (size_t)(w * 64 + fc * 16 + l15) * 256 + ks * 32 + l4 * 8);
            #pragma unroll
            for (int mt = 0; mt < 2; ++mt) {
                const int off = (mt * 16 + l15) * 512 + ((ks * 64 + l4 * 16) ^ aswz);
                ah[mt] = *(const bf16x8*)(lds + off);
                al[mt] = *(const bf16x8*)(lds + 16384 + off);
            }
            #pragma unroll
            for (int mt = 0; mt < 2; ++mt) {
                #pragma unroll
                for (int fc = 0; fc < 2; ++fc)
                    accF[mt][fc] = MFMA(ah[mt], bfF[fc], accF[mt][fc]);
                #pragma unroll
                for (int fc = 0; fc < 4; ++fc) {
                    accL[mt][fc] = MFMA(ah[mt], bw[fc], accL[mt][fc]);
                    accL[mt][fc] = MFMA(al[mt], bw[fc], accL[mt][fc]);
                }
            }
        }

        // prefetch next tile's x (lands during softmax/P5/barrier)
        if (t + 1 < cnt) {
            const float4* xp = (const float4*)(x + (tok0 + 32 + srow) * 256 + sseg * 16);
            pf0 = xp[0]; pf1 = xp[1]; pf2 = xp[2]; pf3 = xp[3];
        }

        // softmax over 64 g (4 frags x 16 lanes), rows = 8 tokens per lane
        #pragma unroll
        for (int mt = 0; mt < 2; ++mt)
            #pragma unroll
            for (int r = 0; r < 4; ++r) {
                float v0 = accL[mt][0][r], v1 = accL[mt][1][r];
                float v2 = accL[mt][2][r], v3 = accL[mt][3][r];
                float m = fmaxf(fmaxf(v0, v1), fmaxf(v2, v3));
                m = fmaxf(m, __shfl_xor(m, 1)); m = fmaxf(m, __shfl_xor(m, 2));
                m = fmaxf(m, __shfl_xor(m, 4)); m = fmaxf(m, __shfl_xor(m, 8));
                float e0 = __expf(v0 - m), e1 = __expf(v1 - m);
                float e2 = __expf(v2 - m), e3 = __expf(v3 - m);
                float s = e0 + e1 + e2 + e3;
                s += __shfl_xor(s, 1); s += __shfl_xor(s, 2);
                s += __shfl_xor(s, 4); s += __shfl_xor(s, 8);
                const float inv = 1.0f / s;
                e0 *= inv; e1 *= inv; e2 *= inv; e3 *= inv;
                accL[mt][0][r] = e0; accL[mt][1][r] = e1;
                accL[mt][2][r] = e2; accL[mt][3][r] = e3;
                nacc[0] += e0; nacc[1] += e1; nacc[2] += e2; nacc[3] += e3;
            }

        // P4: pack sw to bf16 + write swizzled LDS image
        unsigned int pL[2][4][2];
        #pragma unroll
        for (int mt = 0; mt < 2; ++mt)
            #pragma unroll
            for (int fc = 0; fc < 4; ++fc) {
                u16 w0 = f2bf(accL[mt][fc][0]), w1 = f2bf(accL[mt][fc][1]);
                u16 w2 = f2bf(accL[mt][fc][2]), w3 = f2bf(accL[mt][fc][3]);
                pL[mt][fc][0] = (unsigned int)w0 | ((unsigned int)w1 << 16);
                pL[mt][fc][1] = (unsigned int)w2 | ((unsigned int)w3 << 16);
                const int gg = (w * 64 + fc * 16 + l15) * 2;
                #pragma unroll
                for (int r = 0; r < 4; ++r) {
                    const int nloc = mt * 16 + l4 * 4 + r;
                    const int key  = ((((nloc >> 2) & 3) ^ (nloc & 3)) << 4);
                    const u16 val  = (r == 0) ? w0 : (r == 1) ? w1 : (r == 2) ? w2 : w3;
                    *(u16*)(lds + 32768 + ((nloc * 1024 + gg) ^ key)) = val;
                }
            }

        // P5: slice_token partial, pure-register operands (k-permutation trick)
        unsigned int pF[2][2][2];
        #pragma unroll
        for (int mt = 0; mt < 2; ++mt)
            #pragma unroll
            for (int fc = 0; fc < 2; ++fc) {
                pF[mt][fc][0] = pack2(accF[mt][fc][0], accF[mt][fc][1]);
                pF[mt][fc][1] = pack2(accF[mt][fc][2], accF[mt][fc][3]);
            }
        #pragma unroll
        for (int mt2 = 0; mt2 < 2; ++mt2) {
            union { u32x4 u; bf16x8 b; } a;
            a.u = (u32x4){pF[0][mt2][0], pF[0][mt2][1], pF[1][mt2][0], pF[1][mt2][1]};
            #pragma unroll
            for (int nt = 0; nt < 4; ++nt) {
                union { u32x4 u; bf16x8 b; } bb;
                bb.u = (u32x4){pL[0][nt][0], pL[0][nt][1], pL[1][nt][0], pL[1][nt][1]};
                stacc[mt2][nt] = MFMA(a.b, bb.b, stacc[mt2][nt]);
            }
        }
    }

    // final tile copy-out
    __syncthreads();
    {
        const long tokL = (tb + cnt - 1) * 32;
        uint4* dst = (uint4*)(swg + (tokL + srow) * 512);
        #pragma unroll
        for (int q = 0; q < 4; ++q)
            dst[q * 16 + sseg] =
                *(const uint4*)(lds + 32768 + ((srow * 1024 + q * 256 + sseg * 16) ^ skey));
    }

    // epilogue: partial slice_token + norm
    float* pstp = pst + ((size_t)bid * 8 + w) * 2048;
    #pragma unroll
    for (int mt2 = 0; mt2 < 2; ++mt2)
        #pragma unroll
        for (int nt = 0; nt < 4; ++nt)
            #pragma unroll
            for (int r = 0; r < 4; ++r)
                pstp[(mt2 * 16 + l4 * 4 + r) * 64 + nt * 16 + l15] = stacc[mt2][nt][r];
    #pragma unroll
    for (int fc = 0; fc < 4; ++fc) {
        float v = nacc[fc];
        v += __shfl_xor(v, 16); v += __shfl_xor(v, 32);
        if (l4 == 0) pnorm[(size_t)bid * 512 + w * 64 + fc * 16 + l15] = v;
    }
}

// ---------------------------------------------------------------------------
// kC1: reduce pst partials (512) -> stn (raw slice_token numerator, [h][c][g])
// ---------------------------------------------------------------------------
__global__ __launch_bounds__(256) void kC1(
    const float* __restrict__ pst, float* __restrict__ stn)
{
    __shared__ float red[256];
    const int o = blockIdx.x * 128 + (threadIdx.x & 127);
    const int half = threadIdx.x >> 7;
    float s = 0.f;
    for (int b = half * 256; b < half * 256 + 256; ++b)
        s += pst[(size_t)b * 16384 + o];
    red[threadIdx.x] = s;
    __syncthreads();
    if (half == 0) stn[o] = red[threadIdx.x] + red[threadIdx.x + 128];
}

// ---------------------------------------------------------------------------
// kattn: norm reduce + tiny per-head attention over 64 slice tokens
// ---------------------------------------------------------------------------
__global__ __launch_bounds__(64) void kattn(
    const float* __restrict__ stn, const float* __restrict__ pnorm,
    const float* __restrict__ Wq, const float* __restrict__ Wk,
    const float* __restrict__ Wv, float* __restrict__ os)
{
    __shared__ float kl[2048], vl[2048];
    const int h = blockIdx.x, g = threadIdx.x;
    float ng = 0.f;
    for (int b = 0; b < 512; ++b) ng += pnorm[b * 512 + h * 64 + g];
    ng += 1e-5f;
    float s[32];
    #pragma unroll
    for (int d = 0; d < 32; ++d) s[d] = stn[h * 2048 + d * 64 + g] / ng;
    float q[32];
    #pragma unroll
    for (int e = 0; e < 32; ++e) {
        float aq = 0.f, ak = 0.f, av = 0.f;
        #pragma unroll
        for (int d = 0; d < 32; ++d) {
            aq += s[d] * Wq[e * 32 + d];
            ak += s[d] * Wk[e * 32 + d];
            av += s[d] * Wv[e * 32 + d];
        }
        q[e] = aq; kl[g * 32 + e] = ak; vl[g * 32 + e] = av;
    }
    __syncthreads();
    float p[64];
    float mx = -1e30f;
    const float scale = 0.17677669529663689f;
    #pragma unroll
    for (int kk = 0; kk < 64; ++kk) {
        float a = 0.f;
        #pragma unroll
        for (int e = 0; e < 32; ++e) a += q[e] * kl[kk * 32 + e];
        a *= scale; p[kk] = a; mx = fmaxf(mx, a);
    }
    float sum = 0.f;
    #pragma unroll
    for (int kk = 0; kk < 64; ++kk) { p[kk] = __expf(p[kk] - mx); sum += p[kk]; }
    const float inv = 1.0f / sum;
    #pragma unroll
    for (int d = 0; d < 32; ++d) {
        float a = 0.f;
        #pragma unroll
        for (int kk = 0; kk < 64; ++kk) a += p[kk] * inv * vl[kk * 32 + d];
        os[h * 2048 + g * 32 + d] = a;
    }
}

// ---------------------------------------------------------------------------
// kD2: Wc2T[co][hg] = sum_d os[h,g,d] * Wout[co, h*32+d]   (bf16)
// ---------------------------------------------------------------------------
__global__ __launch_bounds__(64) void kD2(
    const float* __restrict__ os, const float* __restrict__ Wout,
    u16* __restrict__ Wc2T)
{
    const int co = blockIdx.x;
    for (int rep = 0; rep < 8; ++rep) {
        const int hg = rep * 64 + threadIdx.x;
        const int h = hg >> 6, g = hg & 63;
        float s = 0.f;
        #pragma unroll
        for (int d = 0; d < 32; ++d)
            s += os[h * 2048 + g * 32 + d] * Wout[co * 256 + h * 32 + d];
        Wc2T[co * 512 + hg] = f2bf(s);
    }
}

// ---------------------------------------------------------------------------
// kE: out = sw @ Wc2T^T + bout  ([200000,512]x[512,256] bf16 MFMA, f32 out)
// ---------------------------------------------------------------------------
__global__ __launch_bounds__(512, 4) void kE(
    const u16* __restrict__ swg, const u16* __restrict__ Wc2T,
    const float* __restrict__ bout, float* __restrict__ y)
{
    __shared__ char lds[65536];
    const int tid = threadIdx.x;
    const int w = tid >> 6;
    const int lane = tid & 63;
    const int l15 = lane & 15;
    const int l4 = lane >> 4;
    const long tok0 = (long)blockIdx.x * 64;

    {
        const int row = tid >> 3, seg = tid & 7;
        const uint4* sp = (const uint4*)(swg + (tok0 + row) * 512 + seg * 64);
        const int base = row * 1024 + seg * 128;
        const int swz = (row & 7) << 4;
        #pragma unroll
        for (int c = 0; c < 8; ++c) {
            uint4 v = sp[c];
            *(uint4*)(lds + ((base + c * 16) ^ swz)) = v;
        }
    }
    __syncthreads();

    const float b0 = bout[w * 32 + l15], b1 = bout[w * 32 + 16 + l15];
    f32x4 acc[4][2];
    #pragma unroll
    for (int mt = 0; mt < 4; ++mt) {
        acc[mt][0] = (f32x4){b0, b0, b0, b0};
        acc[mt][1] = (f32x4){b1, b1, b1, b1};
    }

    const int aswz = (l15 & 7) << 4;
    #pragma unroll 4
    for (int ks = 0; ks < 16; ++ks) {
        bf16x8 bfrag[2];
        #pragma unroll
        for (int fc = 0; fc < 2; ++fc)
            bfrag[fc] = *(const bf16x8*)(Wc2T + (size_t)(w * 32 + fc * 16 + l15) * 512 + ks * 32 + l4 * 8);
        bf16x8 a[4];
        #pragma unroll
        for (int mt = 0; mt < 4; ++mt)
            a[mt] = *(const bf16x8*)(lds + (mt * 16 + l15) * 1024 + ((ks * 64 + l4 * 16) ^ aswz));
        #pragma unroll
        for (int mt = 0; mt < 4; ++mt)
            #pragma unroll
            for (int fc = 0; fc < 2; ++fc)
                acc[mt][fc] = MFMA(a[mt], bfrag[fc], acc[mt][fc]);
    }

    #pragma unroll
    for (int mt = 0; mt < 4; ++mt)
        #pragma unroll
        for (int fc = 0; fc < 2; ++fc)
            #pragma unroll
            for (int r = 0; r < 4; ++r) {
                const long n = tok0 + mt * 16 + l4 * 4 + r;
                y[n * 256 + w * 32 + fc * 16 + l15] = acc[mt][fc][r];
            }
}

// ---------------------------------------------------------------------------
extern "C" void kernel_launch(void* const* d_in, const int* in_sizes, int n_in,
                              void* d_out, int out_size, void* d_ws, size_t ws_size,
                              hipStream_t stream) {
    const float* x       = (const float*)d_in[0];
    const float* Wx      = (const float*)d_in[1];
    const float* bx      = (const float*)d_in[2];
    const float* Wfx     = (const float*)d_in[3];
    const float* bfx     = (const float*)d_in[4];
    const float* Wslice  = (const float*)d_in[5];
    const float* bslice  = (const float*)d_in[6];
    const float* Wq      = (const float*)d_in[7];
    const float* Wk      = (const float*)d_in[8];
    const float* Wv      = (const float*)d_in[9];
    const float* Wout    = (const float*)d_in[10];
    const float* bout    = (const float*)d_in[11];
    const float* temp    = (const float*)d_in[12];

    char* wsb = (char*)d_ws;
    u16*   sw    = (u16*)(wsb);                      // 204,800,000 B
    float* pst   = (float*)(wsb + 204800000);        //  33,554,432 B
    float* pnorm = (float*)(wsb + 238354432);        //   1,048,576 B
    u16*   Wcomb = (u16*)(wsb + 239403008);          //     262,144 B
    float* bcomb = (float*)(wsb + 239665152);        //       2,048 B
    u16*   WfxT  = (u16*)(wsb + 239667200);          //     131,072 B
    u16*   Wc2T  = (u16*)(wsb + 239798272);          //     262,144 B
    float* os    = (float*)(wsb + 240060416);        //      65,536 B
    float* stn   = (float*)(wsb + 240125952);        //      65,536 B
    float* y     = (float*)d_out;

    kprep<<<770, 256, 0, stream>>>(Wx, bx, Wfx, Wslice, bslice, temp, Wcomb, bcomb, WfxT);
    kAB<<<512, 512, 0, stream>>>(x, Wcomb, bcomb, WfxT, bfx, sw, pst, pnorm);
    kC1<<<128, 256, 0, stream>>>(pst, stn);
    kattn<<<8, 64, 0, stream>>>(stn, pnorm, Wq, Wk, Wv, os);
    kD2<<<256, 64, 0, stream>>>(os, Wout, Wc2T);
    kE<<<3125, 512, 0, stream>>>(sw, Wc2T, bout, y);
}

// Round 5
// 1020.415 us; speedup vs baseline: 2.3971x; 1.3188x over previous
//
#include <hip/hip_runtime.h>

typedef unsigned short u16;
typedef __attribute__((ext_vector_type(4))) float f32x4;
typedef __attribute__((ext_vector_type(8))) short bf16x8;
typedef __attribute__((ext_vector_type(4))) unsigned int u32x4;

__device__ __forceinline__ float bf2f(u16 u) {
    union { unsigned int i; float f; } v; v.i = ((unsigned int)u) << 16; return v.f;
}
__device__ __forceinline__ u16 f2bf(float f) {
    union { float f; unsigned int i; } v; v.f = f;
    unsigned int x = v.i;
    return (u16)((x + 0x7fffu + ((x >> 16) & 1u)) >> 16);
}
__device__ __forceinline__ unsigned int pack2(float a, float b) {
    return (unsigned int)f2bf(a) | ((unsigned int)f2bf(b) << 16);
}
__device__ __forceinline__ void split2(float a, float b, unsigned int& h, unsigned int& l) {
    u16 ha = f2bf(a), hb = f2bf(b);
    u16 la = f2bf(a - bf2f(ha)), lb = f2bf(b - bf2f(hb));
    h = (unsigned int)ha | ((unsigned int)hb << 16);
    l = (unsigned int)la | ((unsigned int)lb << 16);
}

__device__ __forceinline__ f32x4 MFMA(bf16x8 a, bf16x8 b, f32x4 c) {
    return __builtin_amdgcn_mfma_f32_16x16x32_bf16(a, b, c, 0, 0, 0);
}

// ---------------------------------------------------------------------------
// kprep: Wcomb[hg][k] = invt_h * sum_d Wslice[g,d]*Wx[h*32+d,k]  (bf16)
//        bcomb[hg]    = invt_h * (sum_d Wslice[g,d]*bx[h*32+d] + bslice[g])
//        WfxT = bf16(Wfx)
// ---------------------------------------------------------------------------
__global__ __launch_bounds__(256) void kprep(
    const float* __restrict__ Wx, const float* __restrict__ bx,
    const float* __restrict__ Wfx, const float* __restrict__ Wslice,
    const float* __restrict__ bslice, const float* __restrict__ temperature,
    u16* __restrict__ Wcomb, float* __restrict__ bcomb, u16* __restrict__ WfxT)
{
    const int gidx = blockIdx.x * 256 + threadIdx.x;
    if (gidx < 131072) {
        const int hg = gidx >> 8, k = gidx & 255;
        const int h = hg >> 6, g = hg & 63;
        float tc = fminf(fmaxf(temperature[h], 0.1f), 5.0f);
        const float invt = 1.0f / tc;
        float s = 0.f;
        #pragma unroll
        for (int d = 0; d < 32; ++d) s += Wslice[g * 32 + d] * Wx[(h * 32 + d) * 256 + k];
        Wcomb[hg * 256 + k] = f2bf(s * invt);
    } else if (gidx < 131072 + 65536) {
        const int i = gidx - 131072;
        WfxT[i] = f2bf(Wfx[i]);
    } else if (gidx < 131072 + 65536 + 512) {
        const int hg = gidx - 131072 - 65536;
        const int h = hg >> 6, g = hg & 63;
        float tc = fminf(fmaxf(temperature[h], 0.1f), 5.0f);
        float s = bslice[g];
        #pragma unroll
        for (int d = 0; d < 32; ++d) s += Wslice[g * 32 + d] * bx[h * 32 + d];
        bcomb[hg] = s / tc;
    }
}

// ---------------------------------------------------------------------------
// kAB: 32-token tiles, 512 thr (wave=head), 64KB LDS, register-only P5.
// LDS: [0,16K) x-hi bf16 [32][256], [16K,32K) x-lo, [32K,64K) sw image.
// launch_bounds (512,2): 256-reg cap so B-operand loads pipeline deeply.
// ---------------------------------------------------------------------------
__global__ __launch_bounds__(512, 2) void kAB(
    const float* __restrict__ x, const u16* __restrict__ Wcomb,
    const float* __restrict__ bcomb, const u16* __restrict__ WfxT,
    const float* __restrict__ bfx,
    u16* __restrict__ swg, float* __restrict__ pst, float* __restrict__ pnorm)
{
    __shared__ char lds[65536];
    const int tid  = threadIdx.x;
    const int w    = tid >> 6;
    const int lane = tid & 63;
    const int l15  = lane & 15;
    const int l4   = lane >> 4;
    const int aswz = (l15 & 7) << 4;

    float bc[4], bfv[2];
    #pragma unroll
    for (int fc = 0; fc < 4; ++fc) bc[fc] = bcomb[w * 64 + fc * 16 + l15];
    #pragma unroll
    for (int fc = 0; fc < 2; ++fc) bfv[fc] = bfx[w * 32 + fc * 16 + l15];

    f32x4 stacc[2][4];
    #pragma unroll
    for (int i = 0; i < 2; ++i)
        #pragma unroll
        for (int j = 0; j < 4; ++j) stacc[i][j] = (f32x4){0.f, 0.f, 0.f, 0.f};
    float nacc[4] = {0.f, 0.f, 0.f, 0.f};

    const int bid  = blockIdx.x;
    const int cnt  = 12 + (bid < 106 ? 1 : 0);     // 512*12 + 106 = 6250 tiles
    const long tb  = (long)bid * 12 + (bid < 106 ? bid : 106);

    const int srow = tid >> 4;                      // 0..31
    const int sseg = tid & 15;                      // 0..15
    const int skey = ((((srow >> 2) & 3) ^ (srow & 3)) << 4);
    const int sbs  = srow * 512 + sseg * 32;
    const int sswz = (srow & 7) << 4;

    float4 pf0, pf1, pf2, pf3;
    {
        const float4* xp = (const float4*)(x + (tb * 32 + srow) * 256 + sseg * 16);
        pf0 = xp[0]; pf1 = xp[1]; pf2 = xp[2]; pf3 = xp[3];
    }

    for (int t = 0; t < cnt; ++t) {
        const long tok0 = (tb + t) * 32;

        if (t) {
            __syncthreads();
            // copy out previous tile's sw image: full-line coalesced rows
            uint4* dst = (uint4*)(swg + (tok0 - 32 + srow) * 512);
            #pragma unroll
            for (int q = 0; q < 4; ++q)
                dst[q * 16 + sseg] =
                    *(const uint4*)(lds + 32768 + ((srow * 1024 + q * 256 + sseg * 16) ^ skey));
        }
        // stage A (hi/lo) from prefetch regs
        {
            unsigned int hw[8], lw[8];
            float4 vv0 = pf0, vv1 = pf1, vv2 = pf2, vv3 = pf3;
            split2(vv0.x, vv0.y, hw[0], lw[0]); split2(vv0.z, vv0.w, hw[1], lw[1]);
            split2(vv1.x, vv1.y, hw[2], lw[2]); split2(vv1.z, vv1.w, hw[3], lw[3]);
            split2(vv2.x, vv2.y, hw[4], lw[4]); split2(vv2.z, vv2.w, hw[5], lw[5]);
            split2(vv3.x, vv3.y, hw[6], lw[6]); split2(vv3.z, vv3.w, hw[7], lw[7]);
            *(uint4*)(lds + (sbs ^ sswz))                = make_uint4(hw[0], hw[1], hw[2], hw[3]);
            *(uint4*)(lds + ((sbs + 16) ^ sswz))         = make_uint4(hw[4], hw[5], hw[6], hw[7]);
            *(uint4*)(lds + 16384 + (sbs ^ sswz))        = make_uint4(lw[0], lw[1], lw[2], lw[3]);
            *(uint4*)(lds + 16384 + ((sbs + 16) ^ sswz)) = make_uint4(lw[4], lw[5], lw[6], lw[7]);
        }
        __syncthreads();

        // merged fx + logits GEMMs over K=256
        f32x4 accF[2][2], accL[2][4];
        #pragma unroll
        for (int mt = 0; mt < 2; ++mt) {
            #pragma unroll
            for (int fc = 0; fc < 2; ++fc)
                accF[mt][fc] = (f32x4){bfv[fc], bfv[fc], bfv[fc], bfv[fc]};
            #pragma unroll
            for (int fc = 0; fc < 4; ++fc)
                accL[mt][fc] = (f32x4){bc[fc], bc[fc], bc[fc], bc[fc]};
        }
        #pragma unroll
        for (int ks = 0; ks < 8; ++ks) {
            bf16x8 bfF[2], bw[4], ah[2], al[2];
            #pragma unroll
            for (int fc = 0; fc < 2; ++fc)
                bfF[fc] = *(const bf16x8*)(WfxT + (size_t)(w * 32 + fc * 16 + l15) * 256 + ks * 32 + l4 * 8);
            #pragma unroll
            for (int fc = 0; fc < 4; ++fc)
                bw[fc] = *(const bf16x8*)(Wcomb + (size_t)(w * 64 + fc * 16 + l15) * 256 + ks * 32 + l4 * 8);
            #pragma unroll
            for (int mt = 0; mt < 2; ++mt) {
                const int off = (mt * 16 + l15) * 512 + ((ks * 64 + l4 * 16) ^ aswz);
                ah[mt] = *(const bf16x8*)(lds + off);
                al[mt] = *(const bf16x8*)(lds + 16384 + off);
            }
            #pragma unroll
            for (int mt = 0; mt < 2; ++mt) {
                #pragma unroll
                for (int fc = 0; fc < 2; ++fc)
                    accF[mt][fc] = MFMA(ah[mt], bfF[fc], accF[mt][fc]);
                #pragma unroll
                for (int fc = 0; fc < 4; ++fc) {
                    accL[mt][fc] = MFMA(ah[mt], bw[fc], accL[mt][fc]);
                    accL[mt][fc] = MFMA(al[mt], bw[fc], accL[mt][fc]);
                }
            }
        }

        // prefetch next tile's x (lands during softmax/P5/barrier)
        if (t + 1 < cnt) {
            const float4* xp = (const float4*)(x + (tok0 + 32 + srow) * 256 + sseg * 16);
            pf0 = xp[0]; pf1 = xp[1]; pf2 = xp[2]; pf3 = xp[3];
        }

        // softmax over 64 g: level-order reductions, 8 independent rows/level
        float mrow[8], srow8[8];
        #pragma unroll
        for (int mt = 0; mt < 2; ++mt)
            #pragma unroll
            for (int r = 0; r < 4; ++r) {
                float v0 = accL[mt][0][r], v1 = accL[mt][1][r];
                float v2 = accL[mt][2][r], v3 = accL[mt][3][r];
                mrow[mt * 4 + r] = fmaxf(fmaxf(v0, v1), fmaxf(v2, v3));
            }
        #pragma unroll
        for (int d = 1; d <= 8; d <<= 1)
            #pragma unroll
            for (int i = 0; i < 8; ++i)
                mrow[i] = fmaxf(mrow[i], __shfl_xor(mrow[i], d));
        #pragma unroll
        for (int mt = 0; mt < 2; ++mt)
            #pragma unroll
            for (int r = 0; r < 4; ++r) {
                const int i = mt * 4 + r;
                float e0 = __expf(accL[mt][0][r] - mrow[i]);
                float e1 = __expf(accL[mt][1][r] - mrow[i]);
                float e2 = __expf(accL[mt][2][r] - mrow[i]);
                float e3 = __expf(accL[mt][3][r] - mrow[i]);
                accL[mt][0][r] = e0; accL[mt][1][r] = e1;
                accL[mt][2][r] = e2; accL[mt][3][r] = e3;
                srow8[i] = e0 + e1 + e2 + e3;
            }
        #pragma unroll
        for (int d = 1; d <= 8; d <<= 1)
            #pragma unroll
            for (int i = 0; i < 8; ++i)
                srow8[i] += __shfl_xor(srow8[i], d);
        #pragma unroll
        for (int mt = 0; mt < 2; ++mt)
            #pragma unroll
            for (int r = 0; r < 4; ++r) {
                const int i = mt * 4 + r;
                const float inv = 1.0f / srow8[i];
                float e0 = accL[mt][0][r] * inv, e1 = accL[mt][1][r] * inv;
                float e2 = accL[mt][2][r] * inv, e3 = accL[mt][3][r] * inv;
                accL[mt][0][r] = e0; accL[mt][1][r] = e1;
                accL[mt][2][r] = e2; accL[mt][3][r] = e3;
                nacc[0] += e0; nacc[1] += e1; nacc[2] += e2; nacc[3] += e3;
            }

        // P4: pack sw to bf16 + write swizzled LDS image
        unsigned int pL[2][4][2];
        #pragma unroll
        for (int mt = 0; mt < 2; ++mt)
            #pragma unroll
            for (int fc = 0; fc < 4; ++fc) {
                u16 w0 = f2bf(accL[mt][fc][0]), w1 = f2bf(accL[mt][fc][1]);
                u16 w2 = f2bf(accL[mt][fc][2]), w3 = f2bf(accL[mt][fc][3]);
                pL[mt][fc][0] = (unsigned int)w0 | ((unsigned int)w1 << 16);
                pL[mt][fc][1] = (unsigned int)w2 | ((unsigned int)w3 << 16);
                const int gg = (w * 64 + fc * 16 + l15) * 2;
                #pragma unroll
                for (int r = 0; r < 4; ++r) {
                    const int nloc = mt * 16 + l4 * 4 + r;
                    const int key  = ((((nloc >> 2) & 3) ^ (nloc & 3)) << 4);
                    const u16 val  = (r == 0) ? w0 : (r == 1) ? w1 : (r == 2) ? w2 : w3;
                    *(u16*)(lds + 32768 + ((nloc * 1024 + gg) ^ key)) = val;
                }
            }

        // P5: slice_token partial, pure-register operands (k-permutation trick)
        unsigned int pF[2][2][2];
        #pragma unroll
        for (int mt = 0; mt < 2; ++mt)
            #pragma unroll
            for (int fc = 0; fc < 2; ++fc) {
                pF[mt][fc][0] = pack2(accF[mt][fc][0], accF[mt][fc][1]);
                pF[mt][fc][1] = pack2(accF[mt][fc][2], accF[mt][fc][3]);
            }
        #pragma unroll
        for (int mt2 = 0; mt2 < 2; ++mt2) {
            union { u32x4 u; bf16x8 b; } a;
            a.u = (u32x4){pF[0][mt2][0], pF[0][mt2][1], pF[1][mt2][0], pF[1][mt2][1]};
            #pragma unroll
            for (int nt = 0; nt < 4; ++nt) {
                union { u32x4 u; bf16x8 b; } bb;
                bb.u = (u32x4){pL[0][nt][0], pL[0][nt][1], pL[1][nt][0], pL[1][nt][1]};
                stacc[mt2][nt] = MFMA(a.b, bb.b, stacc[mt2][nt]);
            }
        }
    }

    // final tile copy-out
    __syncthreads();
    {
        const long tokL = (tb + cnt - 1) * 32;
        uint4* dst = (uint4*)(swg + (tokL + srow) * 512);
        #pragma unroll
        for (int q = 0; q < 4; ++q)
            dst[q * 16 + sseg] =
                *(const uint4*)(lds + 32768 + ((srow * 1024 + q * 256 + sseg * 16) ^ skey));
    }

    // epilogue: partial slice_token + norm
    float* pstp = pst + ((size_t)bid * 8 + w) * 2048;
    #pragma unroll
    for (int mt2 = 0; mt2 < 2; ++mt2)
        #pragma unroll
        for (int nt = 0; nt < 4; ++nt)
            #pragma unroll
            for (int r = 0; r < 4; ++r)
                pstp[(mt2 * 16 + l4 * 4 + r) * 64 + nt * 16 + l15] = stacc[mt2][nt][r];
    #pragma unroll
    for (int fc = 0; fc < 4; ++fc) {
        float v = nacc[fc];
        v += __shfl_xor(v, 16); v += __shfl_xor(v, 32);
        if (l4 == 0) pnorm[(size_t)bid * 512 + w * 64 + fc * 16 + l15] = v;
    }
}

// ---------------------------------------------------------------------------
// kC1: reduce pst partials (512) -> stn (raw slice_token numerator, [h][c][g])
// ---------------------------------------------------------------------------
__global__ __launch_bounds__(256) void kC1(
    const float* __restrict__ pst, float* __restrict__ stn)
{
    __shared__ float red[256];
    const int o = blockIdx.x * 128 + (threadIdx.x & 127);
    const int half = threadIdx.x >> 7;
    float s = 0.f;
    for (int b = half * 256; b < half * 256 + 256; ++b)
        s += pst[(size_t)b * 16384 + o];
    red[threadIdx.x] = s;
    __syncthreads();
    if (half == 0) stn[o] = red[threadIdx.x] + red[threadIdx.x + 128];
}

// ---------------------------------------------------------------------------
// kattn: norm reduce + tiny per-head attention over 64 slice tokens
// ---------------------------------------------------------------------------
__global__ __launch_bounds__(64) void kattn(
    const float* __restrict__ stn, const float* __restrict__ pnorm,
    const float* __restrict__ Wq, const float* __restrict__ Wk,
    const float* __restrict__ Wv, float* __restrict__ os)
{
    __shared__ float kl[2048], vl[2048];
    const int h = blockIdx.x, g = threadIdx.x;
    float ng = 0.f;
    for (int b = 0; b < 512; ++b) ng += pnorm[b * 512 + h * 64 + g];
    ng += 1e-5f;
    float s[32];
    #pragma unroll
    for (int d = 0; d < 32; ++d) s[d] = stn[h * 2048 + d * 64 + g] / ng;
    float q[32];
    #pragma unroll
    for (int e = 0; e < 32; ++e) {
        float aq = 0.f, ak = 0.f, av = 0.f;
        #pragma unroll
        for (int d = 0; d < 32; ++d) {
            aq += s[d] * Wq[e * 32 + d];
            ak += s[d] * Wk[e * 32 + d];
            av += s[d] * Wv[e * 32 + d];
        }
        q[e] = aq; kl[g * 32 + e] = ak; vl[g * 32 + e] = av;
    }
    __syncthreads();
    float p[64];
    float mx = -1e30f;
    const float scale = 0.17677669529663689f;
    #pragma unroll
    for (int kk = 0; kk < 64; ++kk) {
        float a = 0.f;
        #pragma unroll
        for (int e = 0; e < 32; ++e) a += q[e] * kl[kk * 32 + e];
        a *= scale; p[kk] = a; mx = fmaxf(mx, a);
    }
    float sum = 0.f;
    #pragma unroll
    for (int kk = 0; kk < 64; ++kk) { p[kk] = __expf(p[kk] - mx); sum += p[kk]; }
    const float inv = 1.0f / sum;
    #pragma unroll
    for (int d = 0; d < 32; ++d) {
        float a = 0.f;
        #pragma unroll
        for (int kk = 0; kk < 64; ++kk) a += p[kk] * inv * vl[kk * 32 + d];
        os[h * 2048 + g * 32 + d] = a;
    }
}

// ---------------------------------------------------------------------------
// kD2: Wc2T[co][hg] = sum_d os[h,g,d] * Wout[co, h*32+d]   (bf16)
// ---------------------------------------------------------------------------
__global__ __launch_bounds__(64) void kD2(
    const float* __restrict__ os, const float* __restrict__ Wout,
    u16* __restrict__ Wc2T)
{
    const int co = blockIdx.x;
    for (int rep = 0; rep < 8; ++rep) {
        const int hg = rep * 64 + threadIdx.x;
        const int h = hg >> 6, g = hg & 63;
        float s = 0.f;
        #pragma unroll
        for (int d = 0; d < 32; ++d)
            s += os[h * 2048 + g * 32 + d] * Wout[co * 256 + h * 32 + d];
        Wc2T[co * 512 + hg] = f2bf(s);
    }
}

// ---------------------------------------------------------------------------
// kE: out = sw @ Wc2T^T + bout. Persistent GEMM: grid 256 (MUST match cnt
// arithmetic!), ~12 tiles/block, B (Wc2T wave-slice, 128 VGPR) hoisted once;
// sw tile prefetched to regs.
// ---------------------------------------------------------------------------
__global__ __launch_bounds__(512, 2) void kE(
    const u16* __restrict__ swg, const u16* __restrict__ Wc2T,
    const float* __restrict__ bout, float* __restrict__ y)
{
    __shared__ char lds[65536];
    const int tid  = threadIdx.x;
    const int w    = tid >> 6;
    const int lane = tid & 63;
    const int l15  = lane & 15;
    const int l4   = lane >> 4;
    const int aswz = (l15 & 7) << 4;

    const int bid = blockIdx.x;
    const int cnt = 12 + (bid < 53 ? 1 : 0);      // 256*12 + 53 = 3125 tiles
    const long tb = (long)bid * 12 + (bid < 53 ? bid : 53);

    // hoist B: tile-invariant Wc2T wave-slice -> 32 bf16x8 (128 VGPR)
    bf16x8 Breg[16][2];
    #pragma unroll
    for (int ks = 0; ks < 16; ++ks)
        #pragma unroll
        for (int fc = 0; fc < 2; ++fc)
            Breg[ks][fc] = *(const bf16x8*)(Wc2T +
                (size_t)(w * 32 + fc * 16 + l15) * 512 + ks * 32 + l4 * 8);

    const float b0 = bout[w * 32 + l15], b1 = bout[w * 32 + 16 + l15];

    const int row = tid >> 3, seg = tid & 7;      // staging: 64 rows x 8 segs
    const int sbase = row * 1024 + seg * 128;
    const int sswz  = (row & 7) << 4;

    uint4 pf[8];
    {
        const uint4* sp = (const uint4*)(swg + (tb * 64 + row) * 512 + seg * 64);
        #pragma unroll
        for (int c = 0; c < 8; ++c) pf[c] = sp[c];
    }

    for (int t = 0; t < cnt; ++t) {
        const long tok0 = (tb + t) * 64;

        #pragma unroll
        for (int c = 0; c < 8; ++c)
            *(uint4*)(lds + ((sbase + c * 16) ^ sswz)) = pf[c];
        __syncthreads();

        if (t + 1 < cnt) {
            const uint4* sp = (const uint4*)(swg + (tok0 + 64 + row) * 512 + seg * 64);
            #pragma unroll
            for (int c = 0; c < 8; ++c) pf[c] = sp[c];
        }

        f32x4 acc[4][2];
        #pragma unroll
        for (int mt = 0; mt < 4; ++mt) {
            acc[mt][0] = (f32x4){b0, b0, b0, b0};
            acc[mt][1] = (f32x4){b1, b1, b1, b1};
        }

        #pragma unroll
        for (int ks = 0; ks < 16; ++ks) {
            bf16x8 a[4];
            #pragma unroll
            for (int mt = 0; mt < 4; ++mt)
                a[mt] = *(const bf16x8*)(lds + (mt * 16 + l15) * 1024 + ((ks * 64 + l4 * 16) ^ aswz));
            #pragma unroll
            for (int mt = 0; mt < 4; ++mt)
                #pragma unroll
                for (int fc = 0; fc < 2; ++fc)
                    acc[mt][fc] = MFMA(a[mt], Breg[ks][fc], acc[mt][fc]);
        }

        #pragma unroll
        for (int mt = 0; mt < 4; ++mt)
            #pragma unroll
            for (int fc = 0; fc < 2; ++fc)
                #pragma unroll
                for (int r = 0; r < 4; ++r) {
                    const long n = tok0 + mt * 16 + l4 * 4 + r;
                    y[n * 256 + w * 32 + fc * 16 + l15] = acc[mt][fc][r];
                }
        __syncthreads();
    }
}

// ---------------------------------------------------------------------------
extern "C" void kernel_launch(void* const* d_in, const int* in_sizes, int n_in,
                              void* d_out, int out_size, void* d_ws, size_t ws_size,
                              hipStream_t stream) {
    const float* x       = (const float*)d_in[0];
    const float* Wx      = (const float*)d_in[1];
    const float* bx      = (const float*)d_in[2];
    const float* Wfx     = (const float*)d_in[3];
    const float* bfx     = (const float*)d_in[4];
    const float* Wslice  = (const float*)d_in[5];
    const float* bslice  = (const float*)d_in[6];
    const float* Wq      = (const float*)d_in[7];
    const float* Wk      = (const float*)d_in[8];
    const float* Wv      = (const float*)d_in[9];
    const float* Wout    = (const float*)d_in[10];
    const float* bout    = (const float*)d_in[11];
    const float* temp    = (const float*)d_in[12];

    char* wsb = (char*)d_ws;
    u16*   sw    = (u16*)(wsb);                      // 204,800,000 B
    float* pst   = (float*)(wsb + 204800000);        //  33,554,432 B
    float* pnorm = (float*)(wsb + 238354432);        //   1,048,576 B
    u16*   Wcomb = (u16*)(wsb + 239403008);          //     262,144 B
    float* bcomb = (float*)(wsb + 239665152);        //       2,048 B
    u16*   WfxT  = (u16*)(wsb + 239667200);          //     131,072 B
    u16*   Wc2T  = (u16*)(wsb + 239798272);          //     262,144 B
    float* os    = (float*)(wsb + 240060416);        //      65,536 B
    float* stn   = (float*)(wsb + 240125952);        //      65,536 B
    float* y     = (float*)d_out;

    kprep<<<770, 256, 0, stream>>>(Wx, bx, Wfx, Wslice, bslice, temp, Wcomb, bcomb, WfxT);
    kAB<<<512, 512, 0, stream>>>(x, Wcomb, bcomb, WfxT, bfx, sw, pst, pnorm);
    kC1<<<128, 256, 0, stream>>>(pst, stn);
    kattn<<<8, 64, 0, stream>>>(stn, pnorm, Wq, Wk, Wv, os);
    kD2<<<256, 64, 0, stream>>>(os, Wout, Wc2T);
    kE<<<256, 512, 0, stream>>>(sw, Wc2T, bout, y);
}